// Round 10
// baseline (76.710 us; speedup 1.0000x reference)
//
#include <hip/hip_runtime.h>
#include <hip/hip_bf16.h>

#define LQ 4096
#define DD 64
#define NB 4
#define NTOT ((size_t)NB * LQ * DD)
#define NROW ((size_t)NB * LQ)

typedef __attribute__((ext_vector_type(4))) float f32x4;
typedef __attribute__((ext_vector_type(8))) short short8;
typedef __attribute__((ext_vector_type(2))) unsigned int uint2v;
typedef __attribute__((ext_vector_type(4))) unsigned short ushort4v;

static __device__ __forceinline__ unsigned short f2bf(float x) {
  __hip_bfloat16 h = __float2bfloat16(x);
  return __builtin_bit_cast(unsigned short, h);
}
static __device__ __forceinline__ float bf2f(unsigned short u) {
  unsigned int v = ((unsigned int)u) << 16;
  return __builtin_bit_cast(float, v);
}
static __device__ __forceinline__ float ex2(float x) { return __builtin_amdgcn_exp2f(x); }

// async global->LDS, 16B per lane, dest = ldsbase + lane*16
static __device__ __forceinline__ void gl_lds16(const unsigned short* g, unsigned short* l) {
  __builtin_amdgcn_global_load_lds(
      (const __attribute__((address_space(1))) unsigned int*)g,
      (__attribute__((address_space(3))) unsigned int*)l, 16, 0, 0);
}

// score scale folded into log2 domain: s2 = T * (0.125 * log2(e))
#define C1 0.18033688011112042f

// ---------------------------------------------------------------------------
// prep: pure cast Q,K,V -> bf16 (layouts unchanged, [b][i][d])
// ---------------------------------------------------------------------------
__global__ __launch_bounds__(256) void prep_kernel(
    const float* __restrict__ q, const float* __restrict__ k,
    const float* __restrict__ v,
    unsigned short* __restrict__ Qb, unsigned short* __restrict__ Kb,
    unsigned short* __restrict__ Vb)
{
  const int arr = blockIdx.x >> 9;
  const size_t off = (((size_t)(blockIdx.x & 511)) * 256 + threadIdx.x) * 8;
  const float* s = arr == 0 ? q : arr == 1 ? k : v;
  unsigned short* d = arr == 0 ? Qb : arr == 1 ? Kb : Vb;
  const f32x4 x0 = *(const f32x4*)(s + off);
  const f32x4 x1 = *(const f32x4*)(s + off + 4);
  ushort4v o0 = { f2bf(x0[0]), f2bf(x0[1]), f2bf(x0[2]), f2bf(x0[3]) };
  ushort4v o1 = { f2bf(x1[0]), f2bf(x1[1]), f2bf(x1[2]), f2bf(x1[3]) };
  *(ushort4v*)(d + off) = o0;
  *(ushort4v*)(d + off + 4) = o1;
}

// ---------------------------------------------------------------------------
// stats: part_ls[jc][b*LQ + i] = sum_{j in chunk jc} exp2(T[i,j]*C1)
// grid: NB*16*8 blocks of 256. Block: i-tile 256 (4 waves x 64 i), j-chunk 512.
// ---------------------------------------------------------------------------
__global__ __launch_bounds__(256, 2) void stats_kernel(
    const unsigned short* __restrict__ Qb, const unsigned short* __restrict__ Kb,
    float* __restrict__ part_ls)
{
  __shared__ __align__(16) unsigned short stK[3][2048];
  const int bx = blockIdx.x;
  const int jc = bx & 7, it = (bx >> 3) & 15, b = bx >> 7;
  const int tid = threadIdx.x, w = tid >> 6, lane = tid & 63;
  const int l15 = lane & 15, g = lane >> 4;
  const int i0 = it * 256 + w * 64;
  const int jbase = jc * 512;
  const unsigned short* Kbase = Kb + (size_t)b * LQ * DD;

  short8 aq[4][2];
#pragma unroll
  for (int is = 0; is < 4; ++is)
#pragma unroll
    for (int kh = 0; kh < 2; ++kh)
      aq[is][kh] = *(const short8*)(Qb + ((size_t)b * LQ + i0 + is * 16 + l15) * DD + kh * 32 + g * 8);

  float ls[4][4];
#pragma unroll
  for (int is = 0; is < 4; ++is)
#pragma unroll
    for (int qq = 0; qq < 4; ++qq) ls[is][qq] = 0.f;

  const int srow = w * 8 + (lane >> 3);
  const int scol = ((lane & 7) ^ (lane >> 3)) << 3;

  gl_lds16(Kbase + (size_t)(jbase + srow) * DD + scol, &stK[0][w * 512]);
  gl_lds16(Kbase + (size_t)(jbase + 32 + srow) * DD + scol, &stK[1][w * 512]);
  asm volatile("s_waitcnt vmcnt(1)" ::: "memory");
  __builtin_amdgcn_s_barrier();

  for (int itr = 0; itr < 16; ++itr) {
    const int cur = itr % 3;
    const int tn = (itr + 2 < 16) ? itr + 2 : 15;
    gl_lds16(Kbase + (size_t)(jbase + tn * 32 + srow) * DD + scol, &stK[(itr + 2) % 3][w * 512]);

    short8 kf[2][2];
#pragma unroll
    for (int jsub = 0; jsub < 2; ++jsub)
#pragma unroll
      for (int kh = 0; kh < 2; ++kh) {
        const int row = jsub * 16 + l15;
        kf[jsub][kh] = *(const short8*)(&stK[cur][row * 64 + (((kh * 4 + g) ^ (l15 & 7)) << 3)]);
      }
#pragma unroll
    for (int is = 0; is < 4; ++is)
#pragma unroll
      for (int jsub = 0; jsub < 2; ++jsub) {
        f32x4 tt = __builtin_amdgcn_mfma_f32_16x16x32_bf16(
            aq[is][0], kf[jsub][0], (f32x4){0.f, 0.f, 0.f, 0.f}, 0, 0, 0);
        tt = __builtin_amdgcn_mfma_f32_16x16x32_bf16(aq[is][1], kf[jsub][1], tt, 0, 0, 0);
#pragma unroll
        for (int qq = 0; qq < 4; ++qq) ls[is][qq] += ex2(tt[qq] * C1);
      }
    asm volatile("s_waitcnt vmcnt(1)" ::: "memory");
    __builtin_amdgcn_s_barrier();
  }
#pragma unroll
  for (int mask = 1; mask <= 8; mask <<= 1)
#pragma unroll
    for (int is = 0; is < 4; ++is)
#pragma unroll
      for (int qq = 0; qq < 4; ++qq) ls[is][qq] += __shfl_xor(ls[is][qq], mask, 64);
  if (l15 == 0) {
#pragma unroll
    for (int is = 0; is < 4; ++is)
#pragma unroll
      for (int qq = 0; qq < 4; ++qq)
        part_ls[(size_t)jc * NROW + b * LQ + i0 + is * 16 + g * 4 + qq] = ls[is][qq];
  }
}

// ---------------------------------------------------------------------------
// combine: Vs[r][d] = Vb[r][d] / l_r ,  l_r = sum_{jc<8} part_ls[jc][r]
// ---------------------------------------------------------------------------
__global__ __launch_bounds__(256) void combine_kernel(
    const float* __restrict__ part_ls, const unsigned short* __restrict__ Vb,
    unsigned short* __restrict__ Vs)
{
  const size_t base = ((size_t)blockIdx.x * 256 + threadIdx.x) * 8;
  const int r = (int)(base >> 6);
  float l = 0.f;
#pragma unroll
  for (int jc = 0; jc < 8; ++jc) l += part_ls[(size_t)jc * NROW + r];
  const float s = 1.0f / l;
  const ushort4v a = *(const ushort4v*)(Vb + base);
  const ushort4v c = *(const ushort4v*)(Vb + base + 4);
  ushort4v oa = { f2bf(bf2f(a[0]) * s), f2bf(bf2f(a[1]) * s),
                  f2bf(bf2f(a[2]) * s), f2bf(bf2f(a[3]) * s) };
  ushort4v oc = { f2bf(bf2f(c[0]) * s), f2bf(bf2f(c[1]) * s),
                  f2bf(bf2f(c[2]) * s), f2bf(bf2f(c[3]) * s) };
  *(ushort4v*)(Vs + base) = oa;
  *(ushort4v*)(Vs + base + 4) = oc;
}

// ---------------------------------------------------------------------------
// attn_out: out[j][d] = sum_i exp2(T[j,i]*C1) * Vs[i][d]   (fp32, no split)
// grid: NB*64 blocks of 256 (4 waves). Block owns 64 j's; wave w walks
// i-quarter [w*1024, +1024) INDEPENDENTLY (private triple-buffered stage,
// no barriers in loop, counted vmcnt(16) = 2 tiles in flight). Wave owns
// all 64 j x 64 d (round-8 inner body: js=4, 24 MFMA / 11KB LDS per iter).
// Cross-wave i-quarter reduce via LDS at the end.
// ---------------------------------------------------------------------------
__global__ __launch_bounds__(256, 1) void attn_out_kernel(
    const unsigned short* __restrict__ Qb, const unsigned short* __restrict__ Kb,
    const unsigned short* __restrict__ Vs, float* __restrict__ out)
{
  __shared__ __align__(16) unsigned short stage[4][3][4096]; // [wave][buf][Q2048|V2048]
  __shared__ __align__(16) unsigned short Pall[4 * 2176];    // per wave: 4 js x 544

  const int bx = blockIdx.x;
  const int jt = bx & 63;
  const int b  = bx >> 6;
  const int tid = threadIdx.x, w = tid >> 6, lane = tid & 63;
  const int l15 = lane & 15, g = lane >> 4;
  const int j0 = jt * 64;

  const unsigned short* Qbase = Qb + (size_t)b * LQ * DD;
  const unsigned short* Vbase = Vs + (size_t)b * LQ * DD;

  // resident K A-frags: A[m=j=l15][k=d], 4 j-subtiles x 2 d-halves
  short8 ka[4][2];
#pragma unroll
  for (int js = 0; js < 4; ++js)
#pragma unroll
    for (int kh = 0; kh < 2; ++kh)
      ka[js][kh] = *(const short8*)(Kb + ((size_t)b * LQ + j0 + js * 16 + l15) * DD + kh * 32 + g * 8);

  f32x4 acc[4][4];
#pragma unroll
  for (int js = 0; js < 4; ++js)
#pragma unroll
    for (int ds = 0; ds < 4; ++ds) acc[js][ds] = (f32x4){0.f, 0.f, 0.f, 0.f};

  const int ibase = w * 1024;
  // per-instr staging source addressing (fully coalesced 1KB blocks)
  const int qrow = lane >> 3;                 // + 8*kk
  const int qcol = ((lane & 7) ^ (lane >> 3)) << 3;
  const int vrow = (lane >> 5) * 4 + ((lane >> 1) & 3);   // + 8*kk
  const int vcol = (((lane >> 3) & 3) << 4) + ((lane & 1) << 3);

  unsigned short* Pw = &Pall[w * 2176];
  const unsigned pbyte = (unsigned)(size_t)Pw;

#define STAGE(BUF, I0) do { \
    _Pragma("unroll") \
    for (int kk = 0; kk < 4; ++kk) { \
      gl_lds16(Qbase + (size_t)((I0) + kk * 8 + qrow) * DD + qcol, &stage[w][BUF][kk * 512]); \
      gl_lds16(Vbase + (size_t)((I0) + kk * 8 + vrow) * DD + vcol, &stage[w][BUF][2048 + kk * 512]); \
    } \
  } while (0)

  STAGE(0, ibase);
  STAGE(1, ibase + 32);

  for (int itr = 0; itr < 32; ++itr) {
    const int cur = itr % 3;
    const int tn = (itr + 2 < 32) ? itr + 2 : 31;
    STAGE((itr + 2) % 3, ibase + tn * 32);
    // wait for tile `itr` (2 newer tiles = 16 loads may stay in flight)
    asm volatile("s_waitcnt vmcnt(16)" ::: "memory");

    const unsigned sbyte = (unsigned)(size_t)&stage[w][cur][0];

    // Q B-frags from swizzled LDS: B[n=i=l15][k=d]
    short8 qf[2][2];
#pragma unroll
    for (int is = 0; is < 2; ++is)
#pragma unroll
      for (int kh = 0; kh < 2; ++kh) {
        const int row = is * 16 + l15;
        qf[is][kh] = *(const short8*)(&stage[w][cur][row * 64 + (((kh * 4 + g) ^ (l15 & 7)) << 3)]);
      }

    // V B-frags via hw transpose read: B[k=i][n=d]
    unsigned long long v0, v1, v2, v3, v4, v5, v6, v7;
    const unsigned av = sbyte + 4096 + g * 1024 + l15 * 8;
    asm volatile(
        "ds_read_b64_tr_b16 %0, %8\n\t"
        "ds_read_b64_tr_b16 %1, %8 offset:512\n\t"
        "ds_read_b64_tr_b16 %2, %8 offset:128\n\t"
        "ds_read_b64_tr_b16 %3, %8 offset:640\n\t"
        "ds_read_b64_tr_b16 %4, %8 offset:256\n\t"
        "ds_read_b64_tr_b16 %5, %8 offset:768\n\t"
        "ds_read_b64_tr_b16 %6, %8 offset:384\n\t"
        "ds_read_b64_tr_b16 %7, %8 offset:896\n\t"
        "s_waitcnt lgkmcnt(0)"
        : "=&v"(v0), "=&v"(v1), "=&v"(v2), "=&v"(v3),
          "=&v"(v4), "=&v"(v5), "=&v"(v6), "=&v"(v7)
        : "v"(av) : "memory");
    union U { unsigned long long u[2]; short8 s; };
    U vf0, vf1, vf2, vf3;
    vf0.u[0] = v0; vf0.u[1] = v1;
    vf1.u[0] = v2; vf1.u[1] = v3;
    vf2.u[0] = v4; vf2.u[1] = v5;
    vf3.u[0] = v6; vf3.u[1] = v7;

    // T = K_j . Q_i ; P = exp2(T*C1) (V pre-scaled) ; pack -> P LDS [js][i][jl]
#pragma unroll
    for (int js = 0; js < 4; ++js) {
#pragma unroll
      for (int is = 0; is < 2; ++is) {
        f32x4 tt = __builtin_amdgcn_mfma_f32_16x16x32_bf16(
            ka[js][0], qf[is][0], (f32x4){0.f, 0.f, 0.f, 0.f}, 0, 0, 0);
        tt = __builtin_amdgcn_mfma_f32_16x16x32_bf16(ka[js][1], qf[is][1], tt, 0, 0, 0);
        const unsigned a0 = __builtin_bit_cast(unsigned, ex2(tt[0] * C1)) + 0x8000u;
        const unsigned a1 = __builtin_bit_cast(unsigned, ex2(tt[1] * C1)) + 0x8000u;
        const unsigned a2 = __builtin_bit_cast(unsigned, ex2(tt[2] * C1)) + 0x8000u;
        const unsigned a3 = __builtin_bit_cast(unsigned, ex2(tt[3] * C1)) + 0x8000u;
        uint2v uu;
        uu[0] = __builtin_amdgcn_perm(a1, a0, 0x07060302u);
        uu[1] = __builtin_amdgcn_perm(a3, a2, 0x07060302u);
        const int il = is * 16 + l15;
        *(uint2v*)(&Pw[js * 544 + (il >> 2) * 68 + (il & 3) * 16 + g * 4]) = uu;
      }
    }

    // P^T A-frags via tr-read (wait P writes first), then PV
    unsigned long long p0, p1, p2, p3, p4, p5, p6, p7;
    const unsigned ap = pbyte + g * 272 + l15 * 8;
    asm volatile(
        "s_waitcnt lgkmcnt(0)\n\t"
        "ds_read_b64_tr_b16 %0, %8\n\t"
        "ds_read_b64_tr_b16 %1, %8 offset:136\n\t"
        "ds_read_b64_tr_b16 %2, %8 offset:1088\n\t"
        "ds_read_b64_tr_b16 %3, %8 offset:1224\n\t"
        "ds_read_b64_tr_b16 %4, %8 offset:2176\n\t"
        "ds_read_b64_tr_b16 %5, %8 offset:2312\n\t"
        "ds_read_b64_tr_b16 %6, %8 offset:3264\n\t"
        "ds_read_b64_tr_b16 %7, %8 offset:3400\n\t"
        "s_waitcnt lgkmcnt(0)"
        : "=&v"(p0), "=&v"(p1), "=&v"(p2), "=&v"(p3),
          "=&v"(p4), "=&v"(p5), "=&v"(p6), "=&v"(p7)
        : "v"(ap) : "memory");
    U pa[4];
    pa[0].u[0] = p0; pa[0].u[1] = p1;
    pa[1].u[0] = p2; pa[1].u[1] = p3;
    pa[2].u[0] = p4; pa[2].u[1] = p5;
    pa[3].u[0] = p6; pa[3].u[1] = p7;
#pragma unroll
    for (int js = 0; js < 4; ++js) {
      acc[js][0] = __builtin_amdgcn_mfma_f32_16x16x32_bf16(pa[js].s, vf0.s, acc[js][0], 0, 0, 0);
      acc[js][1] = __builtin_amdgcn_mfma_f32_16x16x32_bf16(pa[js].s, vf1.s, acc[js][1], 0, 0, 0);
      acc[js][2] = __builtin_amdgcn_mfma_f32_16x16x32_bf16(pa[js].s, vf2.s, acc[js][2], 0, 0, 0);
      acc[js][3] = __builtin_amdgcn_mfma_f32_16x16x32_bf16(pa[js].s, vf3.s, acc[js][3], 0, 0, 0);
    }
  }
#undef STAGE

  // cross-wave reduce over i-quarters: waves 1..3 dump to LDS, wave 0 sums.
  asm volatile("s_waitcnt vmcnt(0)" ::: "memory");
  __syncthreads();
  float* red = (float*)&stage[0][0][0];   // 3 x 16KB = 48KB (stage is 96KB)
  if (w > 0) {
#pragma unroll
    for (int js = 0; js < 4; ++js)
#pragma unroll
      for (int ds = 0; ds < 4; ++ds)
#pragma unroll
        for (int qq = 0; qq < 4; ++qq)
          red[(w - 1) * 4096 + (js * 16 + g * 4 + qq) * 64 + ds * 16 + l15] = acc[js][ds][qq];
  }
  __syncthreads();
  if (w == 0) {
    float* op = out + ((size_t)b * LQ + j0) * DD;
#pragma unroll
    for (int js = 0; js < 4; ++js)
#pragma unroll
      for (int ds = 0; ds < 4; ++ds)
#pragma unroll
        for (int qq = 0; qq < 4; ++qq) {
          const int idx = (js * 16 + g * 4 + qq) * 64 + ds * 16 + l15;
          op[idx] = acc[js][ds][qq] + red[idx] + red[4096 + idx] + red[8192 + idx];
        }
  }
}

// ---------------------------------------------------------------------------
extern "C" void kernel_launch(void* const* d_in, const int* in_sizes, int n_in,
                              void* d_out, int out_size, void* d_ws, size_t ws_size,
                              hipStream_t stream) {
  const float* q = (const float*)d_in[0];
  const float* k = (const float*)d_in[1];
  const float* v = (const float*)d_in[2];

  unsigned short* Qb = (unsigned short*)d_ws;
  unsigned short* Kb = Qb + NTOT;
  unsigned short* Vb = Kb + NTOT;
  unsigned short* Vs = Vb + NTOT;
  float* part_ls = (float*)(Vs + NTOT);
  float* outp = (float*)d_out;

  prep_kernel<<<1536, 256, 0, stream>>>(q, k, v, Qb, Kb, Vb);
  stats_kernel<<<NB * 16 * 8, 256, 0, stream>>>(Qb, Kb, part_ls);
  combine_kernel<<<512, 256, 0, stream>>>(part_ls, Vb, Vs);
  attn_out_kernel<<<NB * 64, 256, 0, stream>>>(Qb, Kb, Vs, outp);
}

// Round 11
// 58.226 us; speedup vs baseline: 1.3174x; 1.3174x over previous
//
#include <hip/hip_runtime.h>
#include <hip/hip_bf16.h>

#define LQ 4096
#define DD 64
#define NB 4
#define NTOT ((size_t)NB * LQ * DD)
#define NROW ((size_t)NB * LQ)

typedef __attribute__((ext_vector_type(4))) float f32x4;
typedef __attribute__((ext_vector_type(8))) short short8;
typedef __attribute__((ext_vector_type(2))) unsigned int uint2v;
typedef __attribute__((ext_vector_type(4))) unsigned short ushort4v;

static __device__ __forceinline__ unsigned short f2bf(float x) {
  __hip_bfloat16 h = __float2bfloat16(x);
  return __builtin_bit_cast(unsigned short, h);
}
static __device__ __forceinline__ float bf2f(unsigned short u) {
  unsigned int v = ((unsigned int)u) << 16;
  return __builtin_bit_cast(float, v);
}
static __device__ __forceinline__ float ex2(float x) { return __builtin_amdgcn_exp2f(x); }

// async global->LDS, 16B per lane, dest = ldsbase + lane*16
static __device__ __forceinline__ void gl_lds16(const unsigned short* g, unsigned short* l) {
  __builtin_amdgcn_global_load_lds(
      (const __attribute__((address_space(1))) unsigned int*)g,
      (__attribute__((address_space(3))) unsigned int*)l, 16, 0, 0);
}

// score scale folded into log2 domain: s2 = T * (0.125 * log2(e))
#define C1 0.18033688011112042f

// ---------------------------------------------------------------------------
// prep: pure cast Q,K,V -> bf16 (layouts unchanged, [b][i][d])
// ---------------------------------------------------------------------------
__global__ __launch_bounds__(256) void prep_kernel(
    const float* __restrict__ q, const float* __restrict__ k,
    const float* __restrict__ v,
    unsigned short* __restrict__ Qb, unsigned short* __restrict__ Kb,
    unsigned short* __restrict__ Vb)
{
  const int arr = blockIdx.x >> 9;
  const size_t off = (((size_t)(blockIdx.x & 511)) * 256 + threadIdx.x) * 8;
  const float* s = arr == 0 ? q : arr == 1 ? k : v;
  unsigned short* d = arr == 0 ? Qb : arr == 1 ? Kb : Vb;
  const f32x4 x0 = *(const f32x4*)(s + off);
  const f32x4 x1 = *(const f32x4*)(s + off + 4);
  ushort4v o0 = { f2bf(x0[0]), f2bf(x0[1]), f2bf(x0[2]), f2bf(x0[3]) };
  ushort4v o1 = { f2bf(x1[0]), f2bf(x1[1]), f2bf(x1[2]), f2bf(x1[3]) };
  *(ushort4v*)(d + off) = o0;
  *(ushort4v*)(d + off + 4) = o1;
}

// ---------------------------------------------------------------------------
// stats: part_ls[jc][b*LQ + i] = sum_{j in chunk jc} exp2(T[i,j]*C1)
// grid: NB*16*8 blocks of 256. Block: i-tile 256 (4 waves x 64 i), j-chunk 512.
// ---------------------------------------------------------------------------
__global__ __launch_bounds__(256, 2) void stats_kernel(
    const unsigned short* __restrict__ Qb, const unsigned short* __restrict__ Kb,
    float* __restrict__ part_ls)
{
  __shared__ __align__(16) unsigned short stK[3][2048];
  const int bx = blockIdx.x;
  const int jc = bx & 7, it = (bx >> 3) & 15, b = bx >> 7;
  const int tid = threadIdx.x, w = tid >> 6, lane = tid & 63;
  const int l15 = lane & 15, g = lane >> 4;
  const int i0 = it * 256 + w * 64;
  const int jbase = jc * 512;
  const unsigned short* Kbase = Kb + (size_t)b * LQ * DD;

  short8 aq[4][2];
#pragma unroll
  for (int is = 0; is < 4; ++is)
#pragma unroll
    for (int kh = 0; kh < 2; ++kh)
      aq[is][kh] = *(const short8*)(Qb + ((size_t)b * LQ + i0 + is * 16 + l15) * DD + kh * 32 + g * 8);

  float ls[4][4];
#pragma unroll
  for (int is = 0; is < 4; ++is)
#pragma unroll
    for (int qq = 0; qq < 4; ++qq) ls[is][qq] = 0.f;

  const int srow = w * 8 + (lane >> 3);
  const int scol = ((lane & 7) ^ (lane >> 3)) << 3;

  gl_lds16(Kbase + (size_t)(jbase + srow) * DD + scol, &stK[0][w * 512]);
  gl_lds16(Kbase + (size_t)(jbase + 32 + srow) * DD + scol, &stK[1][w * 512]);
  asm volatile("s_waitcnt vmcnt(1)" ::: "memory");
  __builtin_amdgcn_s_barrier();

  for (int itr = 0; itr < 16; ++itr) {
    const int cur = itr % 3;
    const int tn = (itr + 2 < 16) ? itr + 2 : 15;
    gl_lds16(Kbase + (size_t)(jbase + tn * 32 + srow) * DD + scol, &stK[(itr + 2) % 3][w * 512]);

    short8 kf[2][2];
#pragma unroll
    for (int jsub = 0; jsub < 2; ++jsub)
#pragma unroll
      for (int kh = 0; kh < 2; ++kh) {
        const int row = jsub * 16 + l15;
        kf[jsub][kh] = *(const short8*)(&stK[cur][row * 64 + (((kh * 4 + g) ^ (l15 & 7)) << 3)]);
      }
#pragma unroll
    for (int is = 0; is < 4; ++is)
#pragma unroll
      for (int jsub = 0; jsub < 2; ++jsub) {
        f32x4 tt = __builtin_amdgcn_mfma_f32_16x16x32_bf16(
            aq[is][0], kf[jsub][0], (f32x4){0.f, 0.f, 0.f, 0.f}, 0, 0, 0);
        tt = __builtin_amdgcn_mfma_f32_16x16x32_bf16(aq[is][1], kf[jsub][1], tt, 0, 0, 0);
#pragma unroll
        for (int qq = 0; qq < 4; ++qq) ls[is][qq] += ex2(tt[qq] * C1);
      }
    asm volatile("s_waitcnt vmcnt(1)" ::: "memory");
    __builtin_amdgcn_s_barrier();
  }
#pragma unroll
  for (int mask = 1; mask <= 8; mask <<= 1)
#pragma unroll
    for (int is = 0; is < 4; ++is)
#pragma unroll
      for (int qq = 0; qq < 4; ++qq) ls[is][qq] += __shfl_xor(ls[is][qq], mask, 64);
  if (l15 == 0) {
#pragma unroll
    for (int is = 0; is < 4; ++is)
#pragma unroll
      for (int qq = 0; qq < 4; ++qq)
        part_ls[(size_t)jc * NROW + b * LQ + i0 + is * 16 + g * 4 + qq] = ls[is][qq];
  }
}

// ---------------------------------------------------------------------------
// combine: Vs[r][d] = Vb[r][d] / l_r ,  l_r = sum_{jc<8} part_ls[jc][r]
// ---------------------------------------------------------------------------
__global__ __launch_bounds__(256) void combine_kernel(
    const float* __restrict__ part_ls, const unsigned short* __restrict__ Vb,
    unsigned short* __restrict__ Vs)
{
  const size_t base = ((size_t)blockIdx.x * 256 + threadIdx.x) * 8;
  const int r = (int)(base >> 6);
  float l = 0.f;
#pragma unroll
  for (int jc = 0; jc < 8; ++jc) l += part_ls[(size_t)jc * NROW + r];
  const float s = 1.0f / l;
  const ushort4v a = *(const ushort4v*)(Vb + base);
  const ushort4v c = *(const ushort4v*)(Vb + base + 4);
  ushort4v oa = { f2bf(bf2f(a[0]) * s), f2bf(bf2f(a[1]) * s),
                  f2bf(bf2f(a[2]) * s), f2bf(bf2f(a[3]) * s) };
  ushort4v oc = { f2bf(bf2f(c[0]) * s), f2bf(bf2f(c[1]) * s),
                  f2bf(bf2f(c[2]) * s), f2bf(bf2f(c[3]) * s) };
  *(ushort4v*)(Vs + base) = oa;
  *(ushort4v*)(Vs + base + 4) = oc;
}

// ---------------------------------------------------------------------------
// attn_out: out[j][d] = sum_i exp2(T[j,i]*C1) * Vs[i][d]   (fp32, no split)
// grid: NB*64 blocks of 512 (8 waves). Block owns 64 j's; wave w walks
// i-eighth [w*512, +512) INDEPENDENTLY (private double-buffered stage, no
// barriers in loop, counted vmcnt(8) = next tile in flight). Wave owns all
// 64 j x 64 d; P through LDS in two js-halves (fits 160KB with 8 stages).
// Parallel cross-wave reduce at the end (each wave sums 8 j-rows).
// ---------------------------------------------------------------------------
__global__ __launch_bounds__(512, 2) void attn_out_kernel(
    const unsigned short* __restrict__ Qb, const unsigned short* __restrict__ Kb,
    const unsigned short* __restrict__ Vs, float* __restrict__ out)
{
  __shared__ __align__(16) unsigned short stage[8][2][4096]; // 128 KB [wave][buf][Q|V]
  __shared__ __align__(16) unsigned short Pall[8 * 1088];    // 17 KB, per wave 2 js-slots

  const int bx = blockIdx.x;
  const int jt = bx & 63;
  const int b  = bx >> 6;
  const int tid = threadIdx.x, w = tid >> 6, lane = tid & 63;
  const int l15 = lane & 15, g = lane >> 4;
  const int j0 = jt * 64;

  const unsigned short* Qbase = Qb + (size_t)b * LQ * DD;
  const unsigned short* Vbase = Vs + (size_t)b * LQ * DD;

  // resident K A-frags: A[m=j=l15][k=d], 4 j-subtiles x 2 d-halves
  short8 ka[4][2];
#pragma unroll
  for (int js = 0; js < 4; ++js)
#pragma unroll
    for (int kh = 0; kh < 2; ++kh)
      ka[js][kh] = *(const short8*)(Kb + ((size_t)b * LQ + j0 + js * 16 + l15) * DD + kh * 32 + g * 8);

  f32x4 acc[4][4];
#pragma unroll
  for (int js = 0; js < 4; ++js)
#pragma unroll
    for (int ds = 0; ds < 4; ++ds) acc[js][ds] = (f32x4){0.f, 0.f, 0.f, 0.f};

  const int ibase = w * 512;
  // per-instr staging source addressing (fully coalesced 1KB blocks)
  const int qrow = lane >> 3;                 // + 8*kk
  const int qcol = ((lane & 7) ^ (lane >> 3)) << 3;
  const int vrow = (lane >> 5) * 4 + ((lane >> 1) & 3);   // + 8*kk
  const int vcol = (((lane >> 3) & 3) << 4) + ((lane & 1) << 3);

  unsigned short* Pw = &Pall[w * 1088];
  const unsigned pbyte = (unsigned)(size_t)Pw;

#define STAGE(BUF, I0) do { \
    _Pragma("unroll") \
    for (int kk = 0; kk < 4; ++kk) { \
      gl_lds16(Qbase + (size_t)((I0) + kk * 8 + qrow) * DD + qcol, &stage[w][BUF][kk * 512]); \
      gl_lds16(Vbase + (size_t)((I0) + kk * 8 + vrow) * DD + vcol, &stage[w][BUF][2048 + kk * 512]); \
    } \
  } while (0)

  STAGE(0, ibase);

  for (int itr = 0; itr < 16; ++itr) {
    const int cur = itr & 1;
    const int tn = (itr + 1 < 16) ? itr + 1 : itr;
    STAGE(cur ^ 1, ibase + tn * 32);
    // wait for tile `itr` (next tile's 8 loads stay in flight)
    asm volatile("s_waitcnt vmcnt(8)" ::: "memory");

    const unsigned sbyte = (unsigned)(size_t)&stage[w][cur][0];

    // Q B-frags from swizzled LDS: B[n=i=l15][k=d]
    short8 qf[2][2];
#pragma unroll
    for (int is = 0; is < 2; ++is)
#pragma unroll
      for (int kh = 0; kh < 2; ++kh) {
        const int row = is * 16 + l15;
        qf[is][kh] = *(const short8*)(&stage[w][cur][row * 64 + (((kh * 4 + g) ^ (l15 & 7)) << 3)]);
      }

    // V B-frags via hw transpose read: B[k=i][n=d]
    unsigned long long v0, v1, v2, v3, v4, v5, v6, v7;
    const unsigned av = sbyte + 4096 + g * 1024 + l15 * 8;
    asm volatile(
        "ds_read_b64_tr_b16 %0, %8\n\t"
        "ds_read_b64_tr_b16 %1, %8 offset:512\n\t"
        "ds_read_b64_tr_b16 %2, %8 offset:128\n\t"
        "ds_read_b64_tr_b16 %3, %8 offset:640\n\t"
        "ds_read_b64_tr_b16 %4, %8 offset:256\n\t"
        "ds_read_b64_tr_b16 %5, %8 offset:768\n\t"
        "ds_read_b64_tr_b16 %6, %8 offset:384\n\t"
        "ds_read_b64_tr_b16 %7, %8 offset:896\n\t"
        "s_waitcnt lgkmcnt(0)"
        : "=&v"(v0), "=&v"(v1), "=&v"(v2), "=&v"(v3),
          "=&v"(v4), "=&v"(v5), "=&v"(v6), "=&v"(v7)
        : "v"(av) : "memory");
    union U { unsigned long long u[2]; short8 s; };
    U vf0, vf1, vf2, vf3;
    vf0.u[0] = v0; vf0.u[1] = v1;
    vf1.u[0] = v2; vf1.u[1] = v3;
    vf2.u[0] = v4; vf2.u[1] = v5;
    vf3.u[0] = v6; vf3.u[1] = v7;

    // two half-passes over js (P LDS holds 2 js-slots)
#pragma unroll
    for (int h = 0; h < 2; ++h) {
      __builtin_amdgcn_s_setprio(1);
#pragma unroll
      for (int jsl = 0; jsl < 2; ++jsl) {
        const int js = h * 2 + jsl;
#pragma unroll
        for (int is = 0; is < 2; ++is) {
          f32x4 tt = __builtin_amdgcn_mfma_f32_16x16x32_bf16(
              ka[js][0], qf[is][0], (f32x4){0.f, 0.f, 0.f, 0.f}, 0, 0, 0);
          tt = __builtin_amdgcn_mfma_f32_16x16x32_bf16(ka[js][1], qf[is][1], tt, 0, 0, 0);
          const unsigned a0 = __builtin_bit_cast(unsigned, ex2(tt[0] * C1)) + 0x8000u;
          const unsigned a1 = __builtin_bit_cast(unsigned, ex2(tt[1] * C1)) + 0x8000u;
          const unsigned a2 = __builtin_bit_cast(unsigned, ex2(tt[2] * C1)) + 0x8000u;
          const unsigned a3 = __builtin_bit_cast(unsigned, ex2(tt[3] * C1)) + 0x8000u;
          uint2v uu;
          uu[0] = __builtin_amdgcn_perm(a1, a0, 0x07060302u);
          uu[1] = __builtin_amdgcn_perm(a3, a2, 0x07060302u);
          const int il = is * 16 + l15;
          *(uint2v*)(&Pw[jsl * 544 + (il >> 2) * 68 + (il & 3) * 16 + g * 4]) = uu;
        }
      }
      __builtin_amdgcn_s_setprio(0);

      // P^T A-frags via tr-read (wait P writes first), then PV
      unsigned long long p0, p1, p2, p3;
      const unsigned ap = pbyte + g * 272 + l15 * 8;
      asm volatile(
          "s_waitcnt lgkmcnt(0)\n\t"
          "ds_read_b64_tr_b16 %0, %4\n\t"
          "ds_read_b64_tr_b16 %1, %4 offset:136\n\t"
          "ds_read_b64_tr_b16 %2, %4 offset:1088\n\t"
          "ds_read_b64_tr_b16 %3, %4 offset:1224\n\t"
          "s_waitcnt lgkmcnt(0)"
          : "=&v"(p0), "=&v"(p1), "=&v"(p2), "=&v"(p3)
          : "v"(ap) : "memory");
      U pa0, pa1;
      pa0.u[0] = p0; pa0.u[1] = p1;
      pa1.u[0] = p2; pa1.u[1] = p3;
      __builtin_amdgcn_s_setprio(1);
      acc[h*2+0][0] = __builtin_amdgcn_mfma_f32_16x16x32_bf16(pa0.s, vf0.s, acc[h*2+0][0], 0, 0, 0);
      acc[h*2+0][1] = __builtin_amdgcn_mfma_f32_16x16x32_bf16(pa0.s, vf1.s, acc[h*2+0][1], 0, 0, 0);
      acc[h*2+0][2] = __builtin_amdgcn_mfma_f32_16x16x32_bf16(pa0.s, vf2.s, acc[h*2+0][2], 0, 0, 0);
      acc[h*2+0][3] = __builtin_amdgcn_mfma_f32_16x16x32_bf16(pa0.s, vf3.s, acc[h*2+0][3], 0, 0, 0);
      acc[h*2+1][0] = __builtin_amdgcn_mfma_f32_16x16x32_bf16(pa1.s, vf0.s, acc[h*2+1][0], 0, 0, 0);
      acc[h*2+1][1] = __builtin_amdgcn_mfma_f32_16x16x32_bf16(pa1.s, vf1.s, acc[h*2+1][1], 0, 0, 0);
      acc[h*2+1][2] = __builtin_amdgcn_mfma_f32_16x16x32_bf16(pa1.s, vf2.s, acc[h*2+1][2], 0, 0, 0);
      acc[h*2+1][3] = __builtin_amdgcn_mfma_f32_16x16x32_bf16(pa1.s, vf3.s, acc[h*2+1][3], 0, 0, 0);
      __builtin_amdgcn_s_setprio(0);
    }
  }
#undef STAGE

  // parallel cross-wave reduce: every wave dumps acc (128KB = stage reuse),
  // then wave w sums + stores j-rows [w*8, w*8+8).
  asm volatile("s_waitcnt vmcnt(0)" ::: "memory");
  __syncthreads();
  float* red = (float*)&stage[0][0][0];   // 8 x 16KB = 128 KB
#pragma unroll
  for (int js = 0; js < 4; ++js)
#pragma unroll
    for (int ds = 0; ds < 4; ++ds)
#pragma unroll
      for (int qq = 0; qq < 4; ++qq)
        red[w * 4096 + (js * 16 + g * 4 + qq) * 64 + ds * 16 + l15] = acc[js][ds][qq];
  __syncthreads();
  {
    const int lr = lane >> 4;            // 0..3
    const int d0 = (lane & 15) * 4;
    float* op = out + ((size_t)b * LQ + j0 + w * 8) * DD;
#pragma unroll
    for (int rr = 0; rr < 2; ++rr) {
      const int row = rr * 4 + lr;       // 0..7 within this wave's slice
      f32x4 s = (f32x4){0.f, 0.f, 0.f, 0.f};
#pragma unroll
      for (int u = 0; u < 8; ++u) {
        const f32x4 t = *(const f32x4*)&red[u * 4096 + (w * 8 + row) * 64 + d0];
        s[0] += t[0]; s[1] += t[1]; s[2] += t[2]; s[3] += t[3];
      }
      *(f32x4*)(op + row * 64 + d0) = s;
    }
  }
}

// ---------------------------------------------------------------------------
extern "C" void kernel_launch(void* const* d_in, const int* in_sizes, int n_in,
                              void* d_out, int out_size, void* d_ws, size_t ws_size,
                              hipStream_t stream) {
  const float* q = (const float*)d_in[0];
  const float* k = (const float*)d_in[1];
  const float* v = (const float*)d_in[2];

  unsigned short* Qb = (unsigned short*)d_ws;
  unsigned short* Kb = Qb + NTOT;
  unsigned short* Vb = Kb + NTOT;
  unsigned short* Vs = Vb + NTOT;
  float* part_ls = (float*)(Vs + NTOT);
  float* outp = (float*)d_out;

  prep_kernel<<<1536, 256, 0, stream>>>(q, k, v, Qb, Kb, Vb);
  stats_kernel<<<NB * 16 * 8, 256, 0, stream>>>(Qb, Kb, part_ls);
  combine_kernel<<<512, 256, 0, stream>>>(part_ls, Vb, Vs);
  attn_out_kernel<<<NB * 64, 512, 0, stream>>>(Qb, Kb, Vs, outp);
}